// Round 1
// 405.189 us; speedup vs baseline: 1.0359x; 1.0359x over previous
//
#include <hip/hip_runtime.h>
#include <cstdint>
#include <cstddef>

#define B_   2
#define L_   4096
#define DM_  1024
#define DI_  2048
#define DT_  64
#define M_   (B_*L_)      // 8192 rows
#define G_   64           // scan chunks per row
#define CH_  (L_/G_)      // 64 elements per chunk
#define KSPL 8            // split-K factor for dt_low GEMM
#define KSL  (DI_/KSPL)   // 256 per split
#define BK_  32           // BK=64 measured REGRESSIVE (R4) [128-tile path]
#define LDC  136          // C-stage LDS stride in bf16 (272B: 16B-aligned rows)
#define LDCF 68           // C-stage LDS stride in fp32 for EPI=4 (272B)
#define LDC3 132          // C-stage LDS stride in fp32 for EPI=3 (528B, 16B-aligned)

typedef __bf16 bf16;
typedef __bf16 bf16x8 __attribute__((ext_vector_type(8)));
typedef __bf16 bf16x4 __attribute__((ext_vector_type(4)));
typedef float  f32x4  __attribute__((ext_vector_type(4)));

__device__ __forceinline__ float silu_f(float x){ return x / (1.f + __expf(-x)); }
// hw-instruction softplus (v_exp_f32/v_log_f32); |err| << bf16 rounding
__device__ __forceinline__ float softplus_f(float x){
  return fmaxf(x, 0.f) + __logf(1.f + __expf(-fabsf(x)));
}
__device__ __forceinline__ float e_of(float delta, float Ad){
  float ee = __expf(delta * Ad);
  return fminf(fmaxf(ee, 1e-6f), 1.f);
}
__device__ __forceinline__ float a_of(const float* alog, int d){
  float Ad = -__expf(alog[d]);
  return fminf(fmaxf(Ad, -10.f), -1e-6f);
}

// async global->LDS, 16B per lane (m97). LDS dest = wave-uniform base + lane*16.
__device__ __forceinline__ void gl_lds16(const bf16* g, bf16* l){
  __builtin_amdgcn_global_load_lds(
      (const __attribute__((address_space(1))) void*)g,
      (__attribute__((address_space(3))) void*)l, 16, 0, 0);
}

// ---------------- fused fp32 -> bf16 conversion for all 5 weight/input tensors
__global__ __launch_bounds__(256)
void cvt_all_kernel(const float4* __restrict__ s0, bf16x4* __restrict__ d0, int n0,
                    const float4* __restrict__ s1, bf16x4* __restrict__ d1, int n1,
                    const float4* __restrict__ s2, bf16x4* __restrict__ d2, int n2,
                    const float4* __restrict__ s3, bf16x4* __restrict__ d3, int n3,
                    const float4* __restrict__ s4, bf16x4* __restrict__ d4, int n4)
{
  int i = blockIdx.x*256 + threadIdx.x;
  const float4* s; bf16x4* d;
  if      (i < n0)                 { s = s0; d = d0; }
  else if ((i -= n0) < n1)         { s = s1; d = d1; }
  else if ((i -= n1) < n2)         { s = s2; d = d2; }
  else if ((i -= n2) < n3)         { s = s3; d = d3; }
  else if ((i -= n3) < n4)         { s = s4; d = d4; }
  else return;
  float4 v = s[i];
  bf16x4 o = {(bf16)v.x, (bf16)v.y, (bf16)v.z, (bf16)v.w};
  d[i] = o;
}

// =====================================================================
// 256x256-tile, BK=64, 8-wave (2Mx4N) deep-pipelined GEMM (T2+T3+T4+T5).
// C[M,N] = A[M,K] * W[N,K]^T, bf16 in, bf16 out with EPI0 semantics:
//   n0 <  DI_ : plain bf16 store to ob  (xi half)
//   n0 >= DI_ : silu then bf16 store to ob2 (g half)
// Schedule (per K-tile, 4 quadrant-phases):
//   - burst-issue all 8 gl_lds half-tile loads for tile t+1 (buf^1) at
//     tile start (max lookahead under 2-buffer constraint)
//   - ONE counted s_waitcnt vmcnt(8) per tile (vmcnt(0) only on last tile)
//   - ONE raw s_barrier after the wait, ONE at tile end; no drains in loop
//   - per phase: 12x ds_read_b128 -> lgkmcnt(0)+sched_barrier -> setprio(1)
//     -> 16 MFMA -> setprio(0)
// LDS swizzle: physical 16B chunk = logical chunk ^ (row&7), applied on the
// global SOURCE of gl_lds (linear dest) and on the ds_read address — the
// both-sides involution (m173/m201). Spreads the stride-128B fragment reads
// uniformly over all 32 banks.
// =====================================================================
template<int MT, int NT, int KT>
__global__ __launch_bounds__(512, 2)
void gemm256(const bf16* __restrict__ A, const bf16* __restrict__ W,
             bf16* __restrict__ ob, bf16* __restrict__ ob2)
{
  __shared__ __align__(16) char smem[131072];   // A: 2x32KiB | B: 2x32KiB
  char* lA = smem;
  char* lB = smem + 65536;

  const int t    = threadIdx.x;
  const int lane = t & 63;
  const int wave = t >> 6;            // 0..7
  const int wm   = wave >> 2;         // 0..1  (M half)
  const int wn   = wave & 3;          // 0..3  (N quarter)
  const int l16  = lane & 15, quad = lane >> 4;

  // XCD-aware swizzle (nwg = (MT/256)*(NT/256) must be %8==0) then
  // n-fast decomposition: consecutive blocks share the A m-stripe (L2 reuse).
  const int nnt = NT / 256;
  const int nwg = (MT/256) * nnt;
  const int cpx = nwg >> 3;
  int lin = (blockIdx.x & 7) * cpx + (blockIdx.x >> 3);
  const int m0 = (lin / nnt) * 256;
  const int n0 = (lin % nnt) * 256;

  // ---- staging streams: 4 sets of 64 rows per operand, 1 gl_lds each.
  // set s, wave w, lane: row = s*64 + w*8 + (lane>>3); physical chunk = lane&7;
  // logical chunk = (lane&7) ^ (row&7) = (lane&7) ^ (lane>>3).
  const int r8     = lane >> 3;
  const int lchunk = (lane & 7) ^ r8;
  const bf16* ap[4]; const bf16* bp[4];
  #pragma unroll
  for (int s = 0; s < 4; ++s){
    ap[s] = A + (size_t)(m0 + s*64 + wave*8 + r8) * KT + lchunk*8;
    bp[s] = W + (size_t)(n0 + s*64 + wave*8 + r8) * KT + lchunk*8;
  }

  auto stage = [&](int ub){
    #pragma unroll
    for (int s = 0; s < 4; ++s){
      gl_lds16(ap[s], (bf16*)(lA + ub*32768 + s*8192 + wave*1024));
      ap[s] += 64;
    }
    #pragma unroll
    for (int s = 0; s < 4; ++s){
      gl_lds16(bp[s], (bf16*)(lB + ub*32768 + s*8192 + wave*1024));
      bp[s] += 64;
    }
  };

  f32x4 acc[8][4] = {};
  constexpr int NTILES = KT / 64;

  stage(0);                                    // tile 0 -> buf 0
  for (int tt = 0; tt < NTILES; ++tt){
    const int u = tt & 1;
    if (tt + 1 < NTILES){
      stage(u ^ 1);                            // tile t+1 -> other buffer
      asm volatile("s_waitcnt vmcnt(8)" ::: "memory");  // tile t landed; 8 in flight
    } else {
      asm volatile("s_waitcnt vmcnt(0)" ::: "memory");  // drain last tile only
    }
    __builtin_amdgcn_s_barrier();              // all waves' stage(t) visible
    __builtin_amdgcn_sched_barrier(0);
    const char* Ab = lA + u*32768;
    const char* Bb = lB + u*32768;

    #pragma unroll
    for (int ph = 0; ph < 4; ++ph){
      const int qm = ph >> 1, qn = ph & 1;
      bf16x8 af[2][4], bfr[2][2];
      #pragma unroll
      for (int s = 0; s < 2; ++s)
        #pragma unroll
        for (int mi = 0; mi < 4; ++mi){
          const int row = wm*128 + qm*64 + mi*16 + l16;
          af[s][mi] = *(const bf16x8*)(Ab + row*128 +
                        ((((s<<2)|quad) ^ (l16 & 7)) << 4));
        }
      #pragma unroll
      for (int s = 0; s < 2; ++s)
        #pragma unroll
        for (int ni = 0; ni < 2; ++ni){
          const int row = wn*64 + qn*32 + ni*16 + l16;
          bfr[s][ni] = *(const bf16x8*)(Bb + row*128 +
                        ((((s<<2)|quad) ^ (l16 & 7)) << 4));
        }
      asm volatile("s_waitcnt lgkmcnt(0)" ::: "memory");
      __builtin_amdgcn_sched_barrier(0);       // rule #18: pin MFMA after wait
      __builtin_amdgcn_s_setprio(1);
      #pragma unroll
      for (int s = 0; s < 2; ++s)
        #pragma unroll
        for (int mi = 0; mi < 4; ++mi)
          #pragma unroll
          for (int ni = 0; ni < 2; ++ni)
            acc[qm*4+mi][qn*2+ni] = __builtin_amdgcn_mfma_f32_16x16x32_bf16(
                af[s][mi], bfr[s][ni], acc[qm*4+mi][qn*2+ni], 0, 0, 0);
      __builtin_amdgcn_s_setprio(0);
      __builtin_amdgcn_sched_barrier(0);
    }
    __builtin_amdgcn_s_barrier();              // reads of buf u done -> reusable
  }

  // ---- EPI0 epilogue: LDS-staged coalesced bf16x8 stores, 2 passes of 128 rows
  bf16* Cs = (bf16*)smem;                      // stride 264 bf16 = 528 B
  const bool isg  = (n0 >= DI_);
  bf16* outp      = isg ? ob2 : ob;
  const int ncol0 = isg ? (n0 - DI_) : n0;
  #pragma unroll
  for (int pass = 0; pass < 2; ++pass){
    if (wm == pass){
      #pragma unroll
      for (int mi = 0; mi < 8; ++mi)
        #pragma unroll
        for (int ni = 0; ni < 4; ++ni)
          #pragma unroll
          for (int r = 0; r < 4; ++r){
            float v = acc[mi][ni][r];
            if (isg) v = silu_f(v);
            Cs[(mi*16 + quad*4 + r)*264 + wn*64 + ni*16 + l16] = (bf16)v;
          }
    }
    __syncthreads();
    #pragma unroll
    for (int it = 0; it < 8; ++it){
      const int row = it*16 + (t >> 5);
      const int c8  = (t & 31) * 8;
      bf16x8 v = *(const bf16x8*)&Cs[row*264 + c8];
      *(bf16x8*)&outp[(size_t)(m0 + pass*128 + row)*DI_ + ncol0 + c8] = v;
    }
    __syncthreads();
  }
}

// ---------------- GEMM: C[M,N] = A[M,K] * W[N,K]^T, bf16 MFMA ----------------
// m97 K-loop (BK=32, global_load_lds w16, unpadded staging LDS) + LDS-staged
// coalesced epilogue. 128-tile path kept for the small/odd-shape GEMMs.
// EPI: 2 = dt epilogue (softplus/clip -> delta bf16) + FUSED scan pass1
//      3 = plain fp32 store (final output), two 64-row LDS passes
//      4 = split-K partial fp32 (dt_low, N=64), K-slice from blockIdx.z
template<int EPI, int MT, int NT, int KT>
__global__ __launch_bounds__(256)
void gemm_bt(const bf16* __restrict__ A, const bf16* __restrict__ W,
             float* __restrict__ o0, bf16* __restrict__ ob, bf16* __restrict__ ob2,
             const float* __restrict__ bias, const float* __restrict__ alog,
             const bf16* __restrict__ uq, float* __restrict__ Pq,
             float* __restrict__ Fq)
{
  __shared__ char smem[34816];                 // As/Bs (16 KiB) reused as C-stage
  bf16* As = (bf16*)smem;
  bf16* Bs = (bf16*)(smem + 128*BK_*2);
  const int t    = threadIdx.x;
  const int lane = t & 63;
  const int wave = t >> 6;
  const int wm   = wave >> 1, wn = wave & 1;
  const int l16  = lane & 15, quad = lane >> 4;

  // block swizzle: groups of 4 m-tiles iterate n together (W-stripe L2 reuse)
  int m0, n0;
  if (EPI == 4){
    m0 = blockIdx.y * 128; n0 = 0;
  } else {
    const int gx  = NT / 128;
    const int lin = blockIdx.y * gx + blockIdx.x;
    const int grp = lin / (gx * 4);
    const int rem = lin % (gx * 4);
    m0 = (grp * 4 + (rem & 3)) * 128;
    n0 = (rem >> 2) * 128;
  }

  const int srow = (lane >> 2);        // staging: 0..15 within issue
  const int scol = (lane & 3) * 8;     // element col: 0,8,16,24

  // full K stride for A/W rows (EPI4 slices K via kbase)
  const int KFULL = (EPI == 4) ? (KT * KSPL) : KT;
  const int kbase = (EPI == 4) ? (int)blockIdx.z * KT : 0;

  // pointer-increment staging streams (no per-iter 64-bit recompute)
  const int rowA0 = m0 + wave*32 + srow;
  int rB0 = n0 + wave*32 + srow, rB1 = rB0 + 16;
  if (NT < 128){ rB0 = (rB0 >= NT) ? NT-1 : rB0; rB1 = (rB1 >= NT) ? NT-1 : rB1; }
  const bf16* ap0 = A + (size_t)rowA0*KFULL        + kbase + scol;
  const bf16* ap1 = A + (size_t)(rowA0+16)*KFULL   + kbase + scol;
  const bf16* bp0 = W + (size_t)rB0*KFULL          + kbase + scol;
  const bf16* bp1 = W + (size_t)rB1*KFULL          + kbase + scol;
  bf16* lA0 = &As[(wave*32)*BK_];
  bf16* lA1 = &As[(wave*32+16)*BK_];
  bf16* lB0 = &Bs[(wave*32)*BK_];
  bf16* lB1 = &Bs[(wave*32+16)*BK_];

  f32x4 acc[4][4] = {};
  constexpr int kframes = KT / BK_;

  for (int kt = 0; kt < kframes; ++kt){
    gl_lds16(ap0, lA0);  gl_lds16(ap1, lA1);
    gl_lds16(bp0, lB0);  gl_lds16(bp1, lB1);
    ap0 += BK_; ap1 += BK_; bp0 += BK_; bp1 += BK_;
    __syncthreads();
    bf16x8 af[4], bf_[4];
    #pragma unroll
    for (int i = 0; i < 4; ++i){
      af[i]  = *(const bf16x8*)&As[(wm*64 + i*16 + l16)*BK_ + quad*8];
      bf_[i] = *(const bf16x8*)&Bs[(wn*64 + i*16 + l16)*BK_ + quad*8];
    }
    #pragma unroll
    for (int mi = 0; mi < 4; ++mi)
      #pragma unroll
      for (int ni = 0; ni < 4; ++ni)
        acc[mi][ni] = __builtin_amdgcn_mfma_f32_16x16x32_bf16(af[mi], bf_[ni], acc[mi][ni], 0, 0, 0);
    __syncthreads();   // also releases As/Bs for C-stage reuse
  }

  // ---- epilogue. acc C/D layout (m89/m91): col = lane&15, row = quad*4 + reg
  if (EPI == 3){
    // fp32 full-width tile: two 64-row passes through 33 KiB LDS
    float* Cf = (float*)smem;
    #pragma unroll
    for (int pass = 0; pass < 2; ++pass){
      if (wm == pass){
        #pragma unroll
        for (int mi = 0; mi < 4; ++mi)
          #pragma unroll
          for (int ni = 0; ni < 4; ++ni)
            #pragma unroll
            for (int r = 0; r < 4; ++r)
              Cf[(mi*16 + quad*4 + r)*LDC3 + wn*64 + ni*16 + l16] = acc[mi][ni][r];
      }
      __syncthreads();
      #pragma unroll
      for (int it = 0; it < 8; ++it){
        const int row = it*8 + (t >> 5);
        const int c4  = (t & 31) * 4;
        float4 v = *(const float4*)&Cf[row*LDC3 + c4];
        *(float4*)&o0[(size_t)(m0 + pass*64 + row)*NT + n0 + c4] = v;
      }
      __syncthreads();
    }
  } else if (EPI == 4){
    // fp32, N=64: only wn==0 columns valid
    float* Cf = (float*)smem;
    if (wn == 0){
      #pragma unroll
      for (int mi = 0; mi < 4; ++mi)
        #pragma unroll
        for (int ni = 0; ni < 4; ++ni)
          #pragma unroll
          for (int r = 0; r < 4; ++r)
            Cf[(wm*64 + mi*16 + quad*4 + r)*LDCF + ni*16 + l16] = acc[mi][ni][r];
    }
    __syncthreads();
    #pragma unroll
    for (int it = 0; it < 8; ++it){
      const int row = it*16 + (t >> 4);
      const int c4  = (t & 15) * 4;
      float4 v = *(const float4*)&Cf[row*LDCF + c4];
      *(float4*)&o0[((size_t)blockIdx.z*M_ + m0 + row)*DT_ + c4] = v;
    }
  } else {
    // bf16 outputs (EPI 2) via padded LDS stage
    bf16* Cs = (bf16*)smem;
    #pragma unroll
    for (int mi = 0; mi < 4; ++mi){
      #pragma unroll
      for (int ni = 0; ni < 4; ++ni){
        const int n = n0 + wn*64 + ni*16 + l16;
        #pragma unroll
        for (int r = 0; r < 4; ++r){
          float v = acc[mi][ni][r];
          v = softplus_f(v + bias[n]);
          v = fminf(fmaxf(v, 1e-6f), 10.f);      // delta
          Cs[(wm*64 + mi*16 + quad*4 + r)*LDC + wn*64 + ni*16 + l16] = (bf16)v;
        }
      }
    }
    __syncthreads();
    #pragma unroll
    for (int it = 0; it < 8; ++it){
      const int row = it*16 + (t >> 4);
      const int c8  = (t & 15) * 8;
      bf16x8 v = *(const bf16x8*)&Cs[row*LDC + c8];
      *(bf16x8*)&ob[(size_t)(m0+row)*NT + n0 + c8] = v;
    }
    {
      // ---- fused scan pass1: tile rows = chunks {c0, c0+1} of batch b.
      // Uses bf16-rounded delta from LDS (identical to what pass3 reads) ->
      // bit-identical to a standalone pass1.
      const int chunk = t >> 7;            // 0..1
      const int dcol  = t & 127;           // 0..127
      const int dglob = n0 + dcol;
      const float Ad  = a_of(alog, dglob);
      const int b  = m0 >> 12;             // 4096 rows per batch
      const int c0 = (m0 & 4095) >> 6;     // within-batch chunk of tile row 0
      const size_t ubase = (size_t)(m0 + chunk*64)*DI_ + dglob;
      float p = 1.f, f = 0.f;
      for (int i = 0; i < CH_; ++i){
        float dl = (float)Cs[(chunk*64 + i)*LDC + dcol];
        float ee = e_of(dl, Ad);
        float uu = (float)uq[ubase + (size_t)i*DI_];
        f = f*ee + uu;
        p *= ee;
      }
      const size_t o = ((size_t)(b*G_ + c0 + chunk))*DI_ + dglob;
      Pq[o] = p; Fq[o] = f;
    }
  }
}

// ---------------- split-K reduce: dtl = sum_z partial[z] (bf16) ----------------
__global__ __launch_bounds__(256)
void dt_reduce_kernel(const float* __restrict__ part, bf16* __restrict__ dtl){
  const int i = blockIdx.x*256 + threadIdx.x;   // m*DT + n
  float s = 0.f;
  #pragma unroll
  for (int z = 0; z < KSPL; ++z) s += part[(size_t)z*M_*DT_ + i];
  dtl[i] = (bf16)s;
}

// ---------------- depthwise causal conv (K=4) + bias + SiLU ----------------
__global__ __launch_bounds__(256)
void conv_silu_kernel(const bf16* __restrict__ xi, const float* __restrict__ cw,
                      const float* __restrict__ cb, bf16* __restrict__ ubf)
{
  const int idx = blockIdx.x*256 + threadIdx.x;    // (b,l,d) flat, coalesced in d
  const int d = idx & (DI_-1);
  const int l = (idx >> 11) & (L_-1);              // DI_=2^11, L_=2^12
  float s = cb[d];
  #pragma unroll
  for (int k = 0; k < 4; ++k){
    const int ll = l + k - 3;
    if (ll >= 0) s += (float)xi[idx + (k-3)*DI_] * cw[d*4 + k];
  }
  ubf[idx] = (bf16)silu_f(s);
}

// ---------------- scan pass3 (with inlined pass2 prefix) ----------------
__global__ __launch_bounds__(256)
void scan_pass3(const bf16* __restrict__ delta, const bf16* __restrict__ u,
                const bf16* __restrict__ g, const float* __restrict__ P,
                const float* __restrict__ F, const float* __restrict__ alog,
                const float* __restrict__ Dp, bf16* __restrict__ y)
{
  const int d = blockIdx.x*256 + threadIdx.x;
  const int c = blockIdx.y, b = blockIdx.z;
  const float Ad = a_of(alog, d);
  float s = 0.f;
  for (int cc = 0; cc < c; ++cc){
    const size_t o = ((size_t)(b*G_ + cc))*DI_ + d;
    s = F[o] + P[o]*s;
  }
  size_t base = ((size_t)(b*L_ + c*CH_))*DI_ + d;
  const float Dd = Dp[d];
  for (int i = 0; i < CH_; ++i){
    const size_t idx = base + (size_t)i*DI_;
    const float uu = (float)u[idx];
    s = s*e_of((float)delta[idx], Ad) + uu;
    float yy = s + uu*Dd;
    yy = fminf(fmaxf(yy, -1e4f), 1e4f);
    yy *= (float)g[idx];              // g = silu(z), from GEMM1 epilogue
    y[idx] = (bf16)yy;
  }
}

// ---------------- host launch ----------------
extern "C" void kernel_launch(void* const* d_in, const int* in_sizes, int n_in,
                              void* d_out, int out_size, void* d_ws, size_t ws_size,
                              hipStream_t stream)
{
  (void)in_sizes; (void)n_in; (void)out_size; (void)ws_size;
  const float* x        = (const float*)d_in[0];
  const float* in_w     = (const float*)d_in[1];
  const float* conv_w   = (const float*)d_in[2];
  const float* conv_b   = (const float*)d_in[3];
  const float* xproj_w  = (const float*)d_in[4];
  const float* dtproj_w = (const float*)d_in[5];
  const float* dtproj_b = (const float*)d_in[6];
  const float* A_log    = (const float*)d_in[7];
  const float* Dp       = (const float*)d_in[8];
  const float* out_w    = (const float*)d_in[9];

  char* base = (char*)d_ws;
  const size_t MiB = 1024*1024;
  // Region 0 [0,64 MiB): xi_bf(32) [p1] -> part(16) [dt] -> delta_bf(32) [e+scan]
  bf16*  xi_bf = (bf16*) (base + 0);
  float* part  = (float*)(base + 0);          // 8*8192*64*4 = 16 MiB
  bf16*  dl_bf = (bf16*) (base + 0);          // delta, 32 MiB
  bf16*  x_bf  = (bf16*) (base + 32*MiB);     // 16 MiB
  bf16*  w1_bf = (bf16*) (base + 48*MiB);     // 8 MiB
  bf16*  g_bf  = (bf16*) (base + 64*MiB);     // 32 MiB
  bf16*  u_bf  = (bf16*) (base + 96*MiB);     // 32 MiB
  bf16*  y_bf  = (bf16*) (base + 128*MiB);    // 32 MiB
  bf16*  wo_bf = (bf16*) (base + 160*MiB);    // 4 MiB
  bf16*  xp_bf = (bf16*) (base + 164*MiB);    // 0.25 MiB
  bf16*  dp_bf = (bf16*) (base + 165*MiB);    // 0.25 MiB
  bf16*  dtl_bf= (bf16*) (base + 166*MiB);    // 1 MiB
  float* P     = (float*)(base + 167*MiB);    // 1 MiB
  float* F     = (float*)(base + 168*MiB);    // 1 MiB  -> total 169 MiB (fits)

  const int c0 = (M_*DM_)/4, c1 = (2*DI_*DM_)/4, c2 = (DT_*DI_)/4,
            c3 = (DI_*DT_)/4, c4 = (DM_*DI_)/4;
  const int ctot = c0+c1+c2+c3+c4;
  cvt_all_kernel<<<(ctot+255)/256, 256, 0, stream>>>(
      (const float4*)x,        (bf16x4*)x_bf,  c0,
      (const float4*)in_w,     (bf16x4*)w1_bf, c1,
      (const float4*)xproj_w,  (bf16x4*)xp_bf, c2,
      (const float4*)dtproj_w, (bf16x4*)dp_bf, c3,
      (const float4*)out_w,    (bf16x4*)wo_bf, c4);

  // 1) xz = x @ in_proj_w^T ; split -> xi (bf16), g=silu(z) (bf16)
  //    256^2 8-wave deep-pipelined kernel (T2+T3+T4+T5); grid 32*16=512 (%8==0)
  gemm256<M_, 2*DI_, DM_><<<dim3((M_/256)*((2*DI_)/256)), 512, 0, stream>>>(
      x_bf, w1_bf, xi_bf, g_bf);
  // 2) depthwise causal conv + bias + silu -> u (bf16)
  conv_silu_kernel<<<(M_*DI_)/256, 256, 0, stream>>>(xi_bf, conv_w, conv_b, u_bf);
  // 3) dt_low = u @ x_proj_w^T, split-K=8 -> fp32 partials (xi region now dead)
  gemm_bt<4, M_, DT_, KSL><<<dim3(1, M_/128, KSPL), 256, 0, stream>>>(
      u_bf, xp_bf, part, nullptr, nullptr, nullptr,
      nullptr, nullptr, nullptr, nullptr);
  dt_reduce_kernel<<<(M_*DT_)/256, 256, 0, stream>>>(part, dtl_bf);
  // 4) delta = clip(softplus(dtl @ dt_proj_w^T + b)) -> bf16 + fused scan pass1
  gemm_bt<2, M_, DI_, DT_><<<dim3(DI_/128, M_/128), 256, 0, stream>>>(
      dtl_bf, dp_bf, nullptr, dl_bf, nullptr, dtproj_b,
      A_log, u_bf, P, F);
  // 5) scan: prefix from P,F + within-chunk states + skip + gate -> y (bf16)
  scan_pass3<<<dim3(DI_/256, G_, B_), 256, 0, stream>>>(
      dl_bf, u_bf, g_bf, P, F, A_log, Dp, y_bf);
  // 6) out = y @ out_proj_w^T  (fp32 output)
  gemm_bt<3, M_, DM_, DI_><<<dim3(DM_/128, M_/128), 256, 0, stream>>>(
      y_bf, wo_bf, (float*)d_out, nullptr, nullptr, nullptr,
      nullptr, nullptr, nullptr, nullptr);
}

// Round 2
// 399.097 us; speedup vs baseline: 1.0517x; 1.0153x over previous
//
#include <hip/hip_runtime.h>
#include <cstdint>
#include <cstddef>

#define B_   2
#define L_   4096
#define DM_  1024
#define DI_  2048
#define DT_  64
#define M_   (B_*L_)      // 8192 rows
#define G_   64           // scan chunks per row
#define CH_  (L_/G_)      // 64 elements per chunk
#define KSPL 8            // split-K factor for dt_low GEMM
#define KSL  (DI_/KSPL)   // 256 per split
#define BK_  32           // BK=64 measured REGRESSIVE (R4) [128-tile path]
#define LDC  136          // C-stage LDS stride in bf16 (272B: 16B-aligned rows)
#define LDCF 68           // C-stage LDS stride in fp32 for EPI=4 (272B)
#define LDC3 132          // C-stage LDS stride in fp32 for EPI=3 (528B, 16B-aligned)

typedef __bf16 bf16;
typedef __bf16 bf16x8 __attribute__((ext_vector_type(8)));
typedef __bf16 bf16x4 __attribute__((ext_vector_type(4)));
typedef float  f32x4  __attribute__((ext_vector_type(4)));

__device__ __forceinline__ float silu_f(float x){ return x / (1.f + __expf(-x)); }
// hw-instruction softplus (v_exp_f32/v_log_f32); |err| << bf16 rounding
__device__ __forceinline__ float softplus_f(float x){
  return fmaxf(x, 0.f) + __logf(1.f + __expf(-fabsf(x)));
}
__device__ __forceinline__ float e_of(float delta, float Ad){
  float ee = __expf(delta * Ad);
  return fminf(fmaxf(ee, 1e-6f), 1.f);
}
__device__ __forceinline__ float a_of(const float* alog, int d){
  float Ad = -__expf(alog[d]);
  return fminf(fmaxf(Ad, -10.f), -1e-6f);
}

// async global->LDS, 16B per lane (m97). LDS dest = wave-uniform base + lane*16.
__device__ __forceinline__ void gl_lds16(const bf16* g, bf16* l){
  __builtin_amdgcn_global_load_lds(
      (const __attribute__((address_space(1))) void*)g,
      (__attribute__((address_space(3))) void*)l, 16, 0, 0);
}

// ---------------- fused fp32 -> bf16 conversion for all 5 weight/input tensors
__global__ __launch_bounds__(256)
void cvt_all_kernel(const float4* __restrict__ s0, bf16x4* __restrict__ d0, int n0,
                    const float4* __restrict__ s1, bf16x4* __restrict__ d1, int n1,
                    const float4* __restrict__ s2, bf16x4* __restrict__ d2, int n2,
                    const float4* __restrict__ s3, bf16x4* __restrict__ d3, int n3,
                    const float4* __restrict__ s4, bf16x4* __restrict__ d4, int n4)
{
  int i = blockIdx.x*256 + threadIdx.x;
  const float4* s; bf16x4* d;
  if      (i < n0)                 { s = s0; d = d0; }
  else if ((i -= n0) < n1)         { s = s1; d = d1; }
  else if ((i -= n1) < n2)         { s = s2; d = d2; }
  else if ((i -= n2) < n3)         { s = s3; d = d3; }
  else if ((i -= n3) < n4)         { s = s4; d = d4; }
  else return;
  float4 v = s[i];
  bf16x4 o = {(bf16)v.x, (bf16)v.y, (bf16)v.z, (bf16)v.w};
  d[i] = o;
}

// =====================================================================
// 256x256-tile, BK=64, 8-wave (2Mx4N) deep-pipelined GEMM (T2+T3+T4+T5).
// C[M,N] = A[M,K] * W[N,K]^T, bf16 in, bf16 out with EPI0 semantics:
//   n0 <  DI_ : plain bf16 store to ob  (xi half)
//   n0 >= DI_ : silu then bf16 store to ob2 (g half)
// R1 lesson (rocprof): the 4-quadrant phase loop was LDS-READ-BW bound —
// 48 ds_read_b128/wave/K-tile (2x fragment redundancy) = 384 KB/CU/K-tile
// >= 3000 cyc at 128 B/cyc, vs ~614 cyc MFMA/SIMD -> MfmaUtil capped at 26%.
// R2 structure: read each fragment ONCE (24 reads/wave/K-tile), hold in regs:
//   stage(t+1); vmcnt(8); barrier
//   issue 12 ds_read (ks0) | sched_barrier | issue 12 ds_read (ks1)
//   lgkmcnt(12) -> 32 MFMA (ks0)   [ks1 latency hides under ks0 MFMA]
//   lgkmcnt(0)  -> 32 MFMA (ks1)
//   barrier
// LDS swizzle: physical 16B chunk = logical chunk ^ (row&7), applied on the
// global SOURCE of gl_lds (linear dest) and on the ds_read address — the
// both-sides involution (m173/m201). Measured 0 bank conflicts.
// =====================================================================
template<int MT, int NT, int KT>
__global__ __launch_bounds__(512, 2)
void gemm256(const bf16* __restrict__ A, const bf16* __restrict__ W,
             bf16* __restrict__ ob, bf16* __restrict__ ob2)
{
  __shared__ __align__(16) char smem[131072];   // A: 2x32KiB | B: 2x32KiB
  char* lA = smem;
  char* lB = smem + 65536;

  const int t    = threadIdx.x;
  const int lane = t & 63;
  const int wave = t >> 6;            // 0..7
  const int wm   = wave >> 2;         // 0..1  (M half)
  const int wn   = wave & 3;          // 0..3  (N quarter)
  const int l16  = lane & 15, quad = lane >> 4;

  // XCD-aware swizzle (nwg = (MT/256)*(NT/256) must be %8==0) then
  // n-fast decomposition: consecutive blocks share the A m-stripe (L2 reuse).
  const int nnt = NT / 256;
  const int nwg = (MT/256) * nnt;
  const int cpx = nwg >> 3;
  int lin = (blockIdx.x & 7) * cpx + (blockIdx.x >> 3);
  const int m0 = (lin / nnt) * 256;
  const int n0 = (lin % nnt) * 256;

  // ---- staging streams: 4 sets of 64 rows per operand, 1 gl_lds each.
  // set s, wave w, lane: row = s*64 + w*8 + (lane>>3); physical chunk = lane&7;
  // logical chunk = (lane&7) ^ (row&7) = (lane&7) ^ (lane>>3).
  const int r8     = lane >> 3;
  const int lchunk = (lane & 7) ^ r8;
  const bf16* ap[4]; const bf16* bp[4];
  #pragma unroll
  for (int s = 0; s < 4; ++s){
    ap[s] = A + (size_t)(m0 + s*64 + wave*8 + r8) * KT + lchunk*8;
    bp[s] = W + (size_t)(n0 + s*64 + wave*8 + r8) * KT + lchunk*8;
  }

  auto stage = [&](int ub){
    #pragma unroll
    for (int s = 0; s < 4; ++s){
      gl_lds16(ap[s], (bf16*)(lA + ub*32768 + s*8192 + wave*1024));
      ap[s] += 64;
    }
    #pragma unroll
    for (int s = 0; s < 4; ++s){
      gl_lds16(bp[s], (bf16*)(lB + ub*32768 + s*8192 + wave*1024));
      bp[s] += 64;
    }
  };

  f32x4 acc[8][4] = {};
  constexpr int NTILES = KT / 64;

  stage(0);                                    // tile 0 -> buf 0
  for (int tt = 0; tt < NTILES; ++tt){
    const int u = tt & 1;
    if (tt + 1 < NTILES){
      stage(u ^ 1);                            // tile t+1 -> other buffer
      asm volatile("s_waitcnt vmcnt(8)" ::: "memory");  // tile t landed; 8 in flight
    } else {
      asm volatile("s_waitcnt vmcnt(0)" ::: "memory");  // drain last tile only
    }
    __builtin_amdgcn_s_barrier();              // all waves' stage(t) visible
    __builtin_amdgcn_sched_barrier(0);
    const char* Ab = lA + u*32768;
    const char* Bb = lB + u*32768;

    // ---- single-read fragment loads: ks0 group, then ks1 group (order pinned)
    bf16x8 a0[8], a1[8], b0[4], b1[4];
    #pragma unroll
    for (int mi = 0; mi < 8; ++mi){
      const int row = wm*128 + mi*16 + l16;
      a0[mi] = *(const bf16x8*)(Ab + row*128 + ((quad ^ (l16 & 7)) << 4));
    }
    #pragma unroll
    for (int ni = 0; ni < 4; ++ni){
      const int row = wn*64 + ni*16 + l16;
      b0[ni] = *(const bf16x8*)(Bb + row*128 + ((quad ^ (l16 & 7)) << 4));
    }
    __builtin_amdgcn_sched_barrier(0);         // keep ks0 reads before ks1 reads
    #pragma unroll
    for (int mi = 0; mi < 8; ++mi){
      const int row = wm*128 + mi*16 + l16;
      a1[mi] = *(const bf16x8*)(Ab + row*128 + (((4|quad) ^ (l16 & 7)) << 4));
    }
    #pragma unroll
    for (int ni = 0; ni < 4; ++ni){
      const int row = wn*64 + ni*16 + l16;
      b1[ni] = *(const bf16x8*)(Bb + row*128 + (((4|quad) ^ (l16 & 7)) << 4));
    }
    asm volatile("s_waitcnt lgkmcnt(12)" ::: "memory");  // ks0's 12 reads done
    __builtin_amdgcn_sched_barrier(0);         // rule #18: pin MFMA after wait
    __builtin_amdgcn_s_setprio(1);
    #pragma unroll
    for (int mi = 0; mi < 8; ++mi)
      #pragma unroll
      for (int ni = 0; ni < 4; ++ni)
        acc[mi][ni] = __builtin_amdgcn_mfma_f32_16x16x32_bf16(
            a0[mi], b0[ni], acc[mi][ni], 0, 0, 0);
    __builtin_amdgcn_s_setprio(0);
    asm volatile("s_waitcnt lgkmcnt(0)" ::: "memory");   // ks1 reads done
    __builtin_amdgcn_sched_barrier(0);
    __builtin_amdgcn_s_setprio(1);
    #pragma unroll
    for (int mi = 0; mi < 8; ++mi)
      #pragma unroll
      for (int ni = 0; ni < 4; ++ni)
        acc[mi][ni] = __builtin_amdgcn_mfma_f32_16x16x32_bf16(
            a1[mi], b1[ni], acc[mi][ni], 0, 0, 0);
    __builtin_amdgcn_s_setprio(0);
    __builtin_amdgcn_sched_barrier(0);
    __builtin_amdgcn_s_barrier();              // reads of buf u done -> reusable
  }

  // ---- EPI0 epilogue: LDS-staged coalesced bf16x8 stores, 2 passes of 128 rows
  bf16* Cs = (bf16*)smem;                      // stride 264 bf16 = 528 B
  const bool isg  = (n0 >= DI_);
  bf16* outp      = isg ? ob2 : ob;
  const int ncol0 = isg ? (n0 - DI_) : n0;
  #pragma unroll
  for (int pass = 0; pass < 2; ++pass){
    if (wm == pass){
      #pragma unroll
      for (int mi = 0; mi < 8; ++mi)
        #pragma unroll
        for (int ni = 0; ni < 4; ++ni)
          #pragma unroll
          for (int r = 0; r < 4; ++r){
            float v = acc[mi][ni][r];
            if (isg) v = silu_f(v);
            Cs[(mi*16 + quad*4 + r)*264 + wn*64 + ni*16 + l16] = (bf16)v;
          }
    }
    __syncthreads();
    #pragma unroll
    for (int it = 0; it < 8; ++it){
      const int row = it*16 + (t >> 5);
      const int c8  = (t & 31) * 8;
      bf16x8 v = *(const bf16x8*)&Cs[row*264 + c8];
      *(bf16x8*)&outp[(size_t)(m0 + pass*128 + row)*DI_ + ncol0 + c8] = v;
    }
    __syncthreads();
  }
}

// ---------------- GEMM: C[M,N] = A[M,K] * W[N,K]^T, bf16 MFMA ----------------
// m97 K-loop (BK=32, global_load_lds w16, unpadded staging LDS) + LDS-staged
// coalesced epilogue. 128-tile path kept for the small/odd-shape GEMMs.
// EPI: 2 = dt epilogue (softplus/clip -> delta bf16) + FUSED scan pass1
//      3 = plain fp32 store (final output), two 64-row LDS passes
//      4 = split-K partial fp32 (dt_low, N=64), K-slice from blockIdx.z
template<int EPI, int MT, int NT, int KT>
__global__ __launch_bounds__(256)
void gemm_bt(const bf16* __restrict__ A, const bf16* __restrict__ W,
             float* __restrict__ o0, bf16* __restrict__ ob, bf16* __restrict__ ob2,
             const float* __restrict__ bias, const float* __restrict__ alog,
             const bf16* __restrict__ uq, float* __restrict__ Pq,
             float* __restrict__ Fq)
{
  __shared__ char smem[34816];                 // As/Bs (16 KiB) reused as C-stage
  bf16* As = (bf16*)smem;
  bf16* Bs = (bf16*)(smem + 128*BK_*2);
  const int t    = threadIdx.x;
  const int lane = t & 63;
  const int wave = t >> 6;
  const int wm   = wave >> 1, wn = wave & 1;
  const int l16  = lane & 15, quad = lane >> 4;

  // block swizzle: groups of 4 m-tiles iterate n together (W-stripe L2 reuse)
  int m0, n0;
  if (EPI == 4){
    m0 = blockIdx.y * 128; n0 = 0;
  } else {
    const int gx  = NT / 128;
    const int lin = blockIdx.y * gx + blockIdx.x;
    const int grp = lin / (gx * 4);
    const int rem = lin % (gx * 4);
    m0 = (grp * 4 + (rem & 3)) * 128;
    n0 = (rem >> 2) * 128;
  }

  const int srow = (lane >> 2);        // staging: 0..15 within issue
  const int scol = (lane & 3) * 8;     // element col: 0,8,16,24

  // full K stride for A/W rows (EPI4 slices K via kbase)
  const int KFULL = (EPI == 4) ? (KT * KSPL) : KT;
  const int kbase = (EPI == 4) ? (int)blockIdx.z * KT : 0;

  // pointer-increment staging streams (no per-iter 64-bit recompute)
  const int rowA0 = m0 + wave*32 + srow;
  int rB0 = n0 + wave*32 + srow, rB1 = rB0 + 16;
  if (NT < 128){ rB0 = (rB0 >= NT) ? NT-1 : rB0; rB1 = (rB1 >= NT) ? NT-1 : rB1; }
  const bf16* ap0 = A + (size_t)rowA0*KFULL        + kbase + scol;
  const bf16* ap1 = A + (size_t)(rowA0+16)*KFULL   + kbase + scol;
  const bf16* bp0 = W + (size_t)rB0*KFULL          + kbase + scol;
  const bf16* bp1 = W + (size_t)rB1*KFULL          + kbase + scol;
  bf16* lA0 = &As[(wave*32)*BK_];
  bf16* lA1 = &As[(wave*32+16)*BK_];
  bf16* lB0 = &Bs[(wave*32)*BK_];
  bf16* lB1 = &Bs[(wave*32+16)*BK_];

  f32x4 acc[4][4] = {};
  constexpr int kframes = KT / BK_;

  for (int kt = 0; kt < kframes; ++kt){
    gl_lds16(ap0, lA0);  gl_lds16(ap1, lA1);
    gl_lds16(bp0, lB0);  gl_lds16(bp1, lB1);
    ap0 += BK_; ap1 += BK_; bp0 += BK_; bp1 += BK_;
    __syncthreads();
    bf16x8 af[4], bf_[4];
    #pragma unroll
    for (int i = 0; i < 4; ++i){
      af[i]  = *(const bf16x8*)&As[(wm*64 + i*16 + l16)*BK_ + quad*8];
      bf_[i] = *(const bf16x8*)&Bs[(wn*64 + i*16 + l16)*BK_ + quad*8];
    }
    #pragma unroll
    for (int mi = 0; mi < 4; ++mi)
      #pragma unroll
      for (int ni = 0; ni < 4; ++ni)
        acc[mi][ni] = __builtin_amdgcn_mfma_f32_16x16x32_bf16(af[mi], bf_[ni], acc[mi][ni], 0, 0, 0);
    __syncthreads();   // also releases As/Bs for C-stage reuse
  }

  // ---- epilogue. acc C/D layout (m89/m91): col = lane&15, row = quad*4 + reg
  if (EPI == 3){
    // fp32 full-width tile: two 64-row passes through 33 KiB LDS
    float* Cf = (float*)smem;
    #pragma unroll
    for (int pass = 0; pass < 2; ++pass){
      if (wm == pass){
        #pragma unroll
        for (int mi = 0; mi < 4; ++mi)
          #pragma unroll
          for (int ni = 0; ni < 4; ++ni)
            #pragma unroll
            for (int r = 0; r < 4; ++r)
              Cf[(mi*16 + quad*4 + r)*LDC3 + wn*64 + ni*16 + l16] = acc[mi][ni][r];
      }
      __syncthreads();
      #pragma unroll
      for (int it = 0; it < 8; ++it){
        const int row = it*8 + (t >> 5);
        const int c4  = (t & 31) * 4;
        float4 v = *(const float4*)&Cf[row*LDC3 + c4];
        *(float4*)&o0[(size_t)(m0 + pass*64 + row)*NT + n0 + c4] = v;
      }
      __syncthreads();
    }
  } else if (EPI == 4){
    // fp32, N=64: only wn==0 columns valid
    float* Cf = (float*)smem;
    if (wn == 0){
      #pragma unroll
      for (int mi = 0; mi < 4; ++mi)
        #pragma unroll
        for (int ni = 0; ni < 4; ++ni)
          #pragma unroll
          for (int r = 0; r < 4; ++r)
            Cf[(wm*64 + mi*16 + quad*4 + r)*LDCF + ni*16 + l16] = acc[mi][ni][r];
    }
    __syncthreads();
    #pragma unroll
    for (int it = 0; it < 8; ++it){
      const int row = it*16 + (t >> 4);
      const int c4  = (t & 15) * 4;
      float4 v = *(const float4*)&Cf[row*LDCF + c4];
      *(float4*)&o0[((size_t)blockIdx.z*M_ + m0 + row)*DT_ + c4] = v;
    }
  } else {
    // bf16 outputs (EPI 2) via padded LDS stage
    bf16* Cs = (bf16*)smem;
    #pragma unroll
    for (int mi = 0; mi < 4; ++mi){
      #pragma unroll
      for (int ni = 0; ni < 4; ++ni){
        const int n = n0 + wn*64 + ni*16 + l16;
        #pragma unroll
        for (int r = 0; r < 4; ++r){
          float v = acc[mi][ni][r];
          v = softplus_f(v + bias[n]);
          v = fminf(fmaxf(v, 1e-6f), 10.f);      // delta
          Cs[(wm*64 + mi*16 + quad*4 + r)*LDC + wn*64 + ni*16 + l16] = (bf16)v;
        }
      }
    }
    __syncthreads();
    #pragma unroll
    for (int it = 0; it < 8; ++it){
      const int row = it*16 + (t >> 4);
      const int c8  = (t & 15) * 8;
      bf16x8 v = *(const bf16x8*)&Cs[row*LDC + c8];
      *(bf16x8*)&ob[(size_t)(m0+row)*NT + n0 + c8] = v;
    }
    {
      // ---- fused scan pass1: tile rows = chunks {c0, c0+1} of batch b.
      // Uses bf16-rounded delta from LDS (identical to what pass3 reads) ->
      // bit-identical to a standalone pass1.
      const int chunk = t >> 7;            // 0..1
      const int dcol  = t & 127;           // 0..127
      const int dglob = n0 + dcol;
      const float Ad  = a_of(alog, dglob);
      const int b  = m0 >> 12;             // 4096 rows per batch
      const int c0 = (m0 & 4095) >> 6;     // within-batch chunk of tile row 0
      const size_t ubase = (size_t)(m0 + chunk*64)*DI_ + dglob;
      float p = 1.f, f = 0.f;
      for (int i = 0; i < CH_; ++i){
        float dl = (float)Cs[(chunk*64 + i)*LDC + dcol];
        float ee = e_of(dl, Ad);
        float uu = (float)uq[ubase + (size_t)i*DI_];
        f = f*ee + uu;
        p *= ee;
      }
      const size_t o = ((size_t)(b*G_ + c0 + chunk))*DI_ + dglob;
      Pq[o] = p; Fq[o] = f;
    }
  }
}

// ---------------- split-K reduce: dtl = sum_z partial[z] (bf16) ----------------
__global__ __launch_bounds__(256)
void dt_reduce_kernel(const float* __restrict__ part, bf16* __restrict__ dtl){
  const int i = blockIdx.x*256 + threadIdx.x;   // m*DT + n
  float s = 0.f;
  #pragma unroll
  for (int z = 0; z < KSPL; ++z) s += part[(size_t)z*M_*DT_ + i];
  dtl[i] = (bf16)s;
}

// ---------------- depthwise causal conv (K=4) + bias + SiLU ----------------
__global__ __launch_bounds__(256)
void conv_silu_kernel(const bf16* __restrict__ xi, const float* __restrict__ cw,
                      const float* __restrict__ cb, bf16* __restrict__ ubf)
{
  const int idx = blockIdx.x*256 + threadIdx.x;    // (b,l,d) flat, coalesced in d
  const int d = idx & (DI_-1);
  const int l = (idx >> 11) & (L_-1);              // DI_=2^11, L_=2^12
  float s = cb[d];
  #pragma unroll
  for (int k = 0; k < 4; ++k){
    const int ll = l + k - 3;
    if (ll >= 0) s += (float)xi[idx + (k-3)*DI_] * cw[d*4 + k];
  }
  ubf[idx] = (bf16)silu_f(s);
}

// ---------------- scan pass3 (with inlined pass2 prefix) ----------------
__global__ __launch_bounds__(256)
void scan_pass3(const bf16* __restrict__ delta, const bf16* __restrict__ u,
                const bf16* __restrict__ g, const float* __restrict__ P,
                const float* __restrict__ F, const float* __restrict__ alog,
                const float* __restrict__ Dp, bf16* __restrict__ y)
{
  const int d = blockIdx.x*256 + threadIdx.x;
  const int c = blockIdx.y, b = blockIdx.z;
  const float Ad = a_of(alog, d);
  float s = 0.f;
  for (int cc = 0; cc < c; ++cc){
    const size_t o = ((size_t)(b*G_ + cc))*DI_ + d;
    s = F[o] + P[o]*s;
  }
  size_t base = ((size_t)(b*L_ + c*CH_))*DI_ + d;
  const float Dd = Dp[d];
  for (int i = 0; i < CH_; ++i){
    const size_t idx = base + (size_t)i*DI_;
    const float uu = (float)u[idx];
    s = s*e_of((float)delta[idx], Ad) + uu;
    float yy = s + uu*Dd;
    yy = fminf(fmaxf(yy, -1e4f), 1e4f);
    yy *= (float)g[idx];              // g = silu(z), from GEMM1 epilogue
    y[idx] = (bf16)yy;
  }
}

// ---------------- host launch ----------------
extern "C" void kernel_launch(void* const* d_in, const int* in_sizes, int n_in,
                              void* d_out, int out_size, void* d_ws, size_t ws_size,
                              hipStream_t stream)
{
  (void)in_sizes; (void)n_in; (void)out_size; (void)ws_size;
  const float* x        = (const float*)d_in[0];
  const float* in_w     = (const float*)d_in[1];
  const float* conv_w   = (const float*)d_in[2];
  const float* conv_b   = (const float*)d_in[3];
  const float* xproj_w  = (const float*)d_in[4];
  const float* dtproj_w = (const float*)d_in[5];
  const float* dtproj_b = (const float*)d_in[6];
  const float* A_log    = (const float*)d_in[7];
  const float* Dp       = (const float*)d_in[8];
  const float* out_w    = (const float*)d_in[9];

  char* base = (char*)d_ws;
  const size_t MiB = 1024*1024;
  // Region 0 [0,64 MiB): xi_bf(32) [p1] -> part(16) [dt] -> delta_bf(32) [e+scan]
  bf16*  xi_bf = (bf16*) (base + 0);
  float* part  = (float*)(base + 0);          // 8*8192*64*4 = 16 MiB
  bf16*  dl_bf = (bf16*) (base + 0);          // delta, 32 MiB
  bf16*  x_bf  = (bf16*) (base + 32*MiB);     // 16 MiB
  bf16*  w1_bf = (bf16*) (base + 48*MiB);     // 8 MiB
  bf16*  g_bf  = (bf16*) (base + 64*MiB);     // 32 MiB
  bf16*  u_bf  = (bf16*) (base + 96*MiB);     // 32 MiB
  bf16*  y_bf  = (bf16*) (base + 128*MiB);    // 32 MiB
  bf16*  wo_bf = (bf16*) (base + 160*MiB);    // 4 MiB
  bf16*  xp_bf = (bf16*) (base + 164*MiB);    // 0.25 MiB
  bf16*  dp_bf = (bf16*) (base + 165*MiB);    // 0.25 MiB
  bf16*  dtl_bf= (bf16*) (base + 166*MiB);    // 1 MiB
  float* P     = (float*)(base + 167*MiB);    // 1 MiB
  float* F     = (float*)(base + 168*MiB);    // 1 MiB  -> total 169 MiB (fits)

  const int c0 = (M_*DM_)/4, c1 = (2*DI_*DM_)/4, c2 = (DT_*DI_)/4,
            c3 = (DI_*DT_)/4, c4 = (DM_*DI_)/4;
  const int ctot = c0+c1+c2+c3+c4;
  cvt_all_kernel<<<(ctot+255)/256, 256, 0, stream>>>(
      (const float4*)x,        (bf16x4*)x_bf,  c0,
      (const float4*)in_w,     (bf16x4*)w1_bf, c1,
      (const float4*)xproj_w,  (bf16x4*)xp_bf, c2,
      (const float4*)dtproj_w, (bf16x4*)dp_bf, c3,
      (const float4*)out_w,    (bf16x4*)wo_bf, c4);

  // 1) xz = x @ in_proj_w^T ; split -> xi (bf16), g=silu(z) (bf16)
  //    256^2 8-wave deep-pipelined kernel (T2+T3+T4+T5); grid 32*16=512 (%8==0)
  gemm256<M_, 2*DI_, DM_><<<dim3((M_/256)*((2*DI_)/256)), 512, 0, stream>>>(
      x_bf, w1_bf, xi_bf, g_bf);
  // 2) depthwise causal conv + bias + silu -> u (bf16)
  conv_silu_kernel<<<(M_*DI_)/256, 256, 0, stream>>>(xi_bf, conv_w, conv_b, u_bf);
  // 3) dt_low = u @ x_proj_w^T, split-K=8 -> fp32 partials (xi region now dead)
  gemm_bt<4, M_, DT_, KSL><<<dim3(1, M_/128, KSPL), 256, 0, stream>>>(
      u_bf, xp_bf, part, nullptr, nullptr, nullptr,
      nullptr, nullptr, nullptr, nullptr);
  dt_reduce_kernel<<<(M_*DT_)/256, 256, 0, stream>>>(part, dtl_bf);
  // 4) delta = clip(softplus(dtl @ dt_proj_w^T + b)) -> bf16 + fused scan pass1
  gemm_bt<2, M_, DI_, DT_><<<dim3(DI_/128, M_/128), 256, 0, stream>>>(
      dtl_bf, dp_bf, nullptr, dl_bf, nullptr, dtproj_b,
      A_log, u_bf, P, F);
  // 5) scan: prefix from P,F + within-chunk states + skip + gate -> y (bf16)
  scan_pass3<<<dim3(DI_/256, G_, B_), 256, 0, stream>>>(
      dl_bf, u_bf, g_bf, P, F, A_log, Dp, y_bf);
  // 6) out = y @ out_proj_w^T  (fp32 output)
  gemm_bt<3, M_, DM_, DI_><<<dim3(DM_/128, M_/128), 256, 0, stream>>>(
      y_bf, wo_bf, (float*)d_out, nullptr, nullptr, nullptr,
      nullptr, nullptr, nullptr, nullptr);
}